// Round 5
// baseline (383.123 us; speedup 1.0000x reference)
//
#include <hip/hip_runtime.h>
#include <hip/hip_bf16.h>

#define NEG_SLOPE 0.2f

typedef __attribute__((ext_vector_type(8))) short bf16x8v;
typedef __attribute__((ext_vector_type(4))) float f32x4;

__device__ __forceinline__ unsigned f2bf_bits(float f) {
    unsigned u = __float_as_uint(f);
    return (u + 0x7fffu + ((u >> 16) & 1u)) >> 16;   // RNE fp32 -> bf16 bits
}
__device__ __forceinline__ float bflo(unsigned u) { return __uint_as_float(u << 16); }
__device__ __forceinline__ float bfhi(unsigned u) { return __uint_as_float(u & 0xffff0000u); }

// ---------------------------------------------------------------------------
// K0: zero the degree array (replaces hipMemsetAsync; graph-capture-safe).
// ---------------------------------------------------------------------------
__global__ __launch_bounds__(256) void zero_deg(int* __restrict__ deg, int N) {
    int i = blockIdx.x * 256 + threadIdx.x;
    if (i < N) deg[i] = 0;
}

// ---------------------------------------------------------------------------
// K1: blocks [0,72): build extended B^T [144][128] bf16 (prep_w).
//     blocks [72,72+nEb): count in-degrees via global atomics (1024 edges/blk).
// ---------------------------------------------------------------------------
__global__ __launch_bounds__(256) void prep_count(const float* __restrict__ W,
                                                  const float* __restrict__ a_src,
                                                  const float* __restrict__ a_dst,
                                                  short* __restrict__ WtE,
                                                  const int* __restrict__ ei, int E,
                                                  int* __restrict__ deg) {
    const int t = threadIdx.x;
    const int blk = blockIdx.x;
    if (blk < 72) {                       // ---- prep_w: 72*256 = 18432 elems
        int id = blk * 256 + t;
        int n = id >> 7, k = id & 127;
        float v;
        if (n < 128) {
            v = W[k * 128 + n];
        } else if (n < 136) {
            int hh = n - 128; float s = 0.f;
#pragma unroll
            for (int d = 0; d < 16; ++d) s += W[k * 128 + hh * 16 + d] * a_src[hh * 16 + d];
            v = s;
        } else {
            int hh = n - 136; float s = 0.f;
#pragma unroll
            for (int d = 0; d < 16; ++d) s += W[k * 128 + hh * 16 + d] * a_dst[hh * 16 + d];
            v = s;
        }
        WtE[id] = (short)f2bf_bits(v);
        return;
    }
    const int base = (blk - 72) * 1024;
#pragma unroll
    for (int k = 0; k < 4; ++k) {
        int i = base + k * 256 + t;
        if (i < E) atomicAdd(&deg[ei[E + i]], 1);
    }
}

// ---------------------------------------------------------------------------
// K2: per-block (1024 nodes) exclusive scan of deg -> rowS (local), bsum[blk].
// ---------------------------------------------------------------------------
__global__ __launch_bounds__(1024) void scan1(const int* __restrict__ deg, int N,
                                              int* __restrict__ rowS,
                                              int* __restrict__ bsum) {
    __shared__ int wpart[16];
    const int t = threadIdx.x;
    const int i = blockIdx.x * 1024 + t;
    int d = (i < N) ? deg[i] : 0;
    int lane = t & 63, wid = t >> 6;
    int sc = d;
#pragma unroll
    for (int off = 1; off < 64; off <<= 1) { int u = __shfl_up(sc, off); if (lane >= off) sc += u; }
    if (lane == 63) wpart[wid] = sc;
    __syncthreads();
    if (wid == 0 && lane < 16) {
        int wv = wpart[lane], wsum = wv;
#pragma unroll
        for (int off = 1; off < 16; off <<= 1) { int u = __shfl_up(wsum, off); if (lane >= off) wsum += u; }
        wpart[lane] = wsum - wv;
    }
    __syncthreads();
    int excl = sc - d + wpart[wid];
    if (i < N) rowS[i] = excl;
    if (t == 1023) bsum[blockIdx.x] = excl + d;
}

// ---------------------------------------------------------------------------
// K3: exclusive scan of the (<=128) block sums, in place. One block, 128 thr.
// ---------------------------------------------------------------------------
__global__ __launch_bounds__(128) void scan2(int* __restrict__ bsum, int nb) {
    __shared__ int w0;
    const int t = threadIdx.x;
    int v = (t < nb) ? bsum[t] : 0;
    int lane = t & 63, wid = t >> 6;
    int sc = v;
#pragma unroll
    for (int off = 1; off < 64; off <<= 1) { int u = __shfl_up(sc, off); if (lane >= off) sc += u; }
    if (t == 63) w0 = sc;
    __syncthreads();
    int incl = sc + (wid ? w0 : 0);
    if (t < nb) bsum[t] = incl - v;
}

// ---------------------------------------------------------------------------
// K4: rowS[i] += blockOff; rowE[i] = rowS[i]+deg[i]; cur[i] = rowS[i].
// ---------------------------------------------------------------------------
__global__ __launch_bounds__(256) void fixup(const int* __restrict__ deg,
                                             const int* __restrict__ boff, int N,
                                             int* __restrict__ rowS,
                                             int* __restrict__ rowE,
                                             int* __restrict__ cur) {
    int i = blockIdx.x * 256 + threadIdx.x;
    if (i < N) {
        int r = rowS[i] + boff[i >> 10];
        rowS[i] = r;
        rowE[i] = r + deg[i];
        cur[i] = r;
    }
}

// ---------------------------------------------------------------------------
// K5: blocks [0,gb): MFMA GEMM [h | as | ad] = bf16(x) @ B[128,144].
//     blocks [gb,gb+nEb): scatter edges into CSR (pos = atomicAdd(cur[dst])).
//     Independent work fused into one dispatch (both 256-thread blocks).
// ---------------------------------------------------------------------------
__global__ __launch_bounds__(256) void gemm_scatter(const float* __restrict__ x,
                                                    const short* __restrict__ WtE,
                                                    short* __restrict__ hout,
                                                    float* __restrict__ as,
                                                    float* __restrict__ ad, int N, int gb,
                                                    const int* __restrict__ ei, int E,
                                                    int* __restrict__ cur,
                                                    int* __restrict__ sortedSrc) {
    __shared__ short xs[64 * 136];
    __shared__ short wt[144 * 136];
    const int tid = threadIdx.x;

    if (blockIdx.x >= gb) {               // ---- scatter path: 1024 edges/block
        const int base = (blockIdx.x - gb) * 1024;
#pragma unroll
        for (int k = 0; k < 4; ++k) {
            int i = base + k * 256 + tid;
            if (i < E) {
                int s = ei[i], d = ei[E + i];
                int pos = atomicAdd(&cur[d], 1);
                sortedSrc[pos] = s;
            }
        }
        return;
    }

    const int r0 = blockIdx.x * 64;
#pragma unroll
    for (int p = 0; p < 9; ++p) {
        int idx = p * 256 + tid;           // 2304 chunks of 8 shorts
        int n = idx >> 4, kk = (idx & 15) * 8;
        *(uint4*)&wt[n * 136 + kk] = *(const uint4*)(WtE + n * 128 + kk);
    }
#pragma unroll
    for (int p = 0; p < 8; ++p) {
        int lin = p * 1024 + tid * 4;
        int row = lin >> 7, k = lin & 127;
        int gr = r0 + row;
        int grc = gr < N ? gr : N - 1;
        float4 v = *(const float4*)(x + (size_t)grc * 128 + k);
        unsigned p0 = f2bf_bits(v.x) | (f2bf_bits(v.y) << 16);
        unsigned p1 = f2bf_bits(v.z) | (f2bf_bits(v.w) << 16);
        *(uint2*)&xs[row * 136 + k] = make_uint2(p0, p1);
    }
    __syncthreads();

    const int wv = tid >> 6;
    const int lane = tid & 63;
    const int lc = lane & 15, quad = lane >> 4;
    f32x4 acc[9];
#pragma unroll
    for (int c = 0; c < 9; ++c) acc[c] = (f32x4){0.f, 0.f, 0.f, 0.f};
    const short* aB = &xs[(wv * 16 + lc) * 136 + quad * 8];
    const short* bB = &wt[lc * 136 + quad * 8];
#pragma unroll
    for (int kc = 0; kc < 4; ++kc) {
        bf16x8v af = *(const bf16x8v*)(aB + kc * 32);
#pragma unroll
        for (int c = 0; c < 9; ++c) {
            bf16x8v bf = *(const bf16x8v*)(bB + c * (16 * 136) + kc * 32);
            acc[c] = __builtin_amdgcn_mfma_f32_16x16x32_bf16(af, bf, acc[c], 0, 0, 0);
        }
    }

    const int rowb = r0 + wv * 16 + quad * 4;
#pragma unroll
    for (int c = 0; c < 8; ++c) {
#pragma unroll
        for (int r = 0; r < 4; ++r) {
            int row = rowb + r;
            if (row < N) hout[(size_t)row * 128 + c * 16 + lc] = (short)f2bf_bits(acc[c][r]);
        }
    }
    // alpha columns: lc<8 -> as head lc; lc>=8 -> ad head lc-8
#pragma unroll
    for (int r = 0; r < 4; ++r) {
        int row = rowb + r;
        if (row < N) {
            if (lc < 8) as[row * 8 + lc] = acc[8][r];
            else        ad[row * 8 + (lc - 8)] = acc[8][r];
        }
    }
}

// ---------------------------------------------------------------------------
// Aggregate v5 (unchanged, measured best): one wave per dst node; lane =
// channel-pair. Lane l owns output channels 2l,2l+1 (head = l>>3). Per edge:
// each lane loads one dword of the h row (coalesced 256B/edge) and FMAs into
// a private f32x2; dsum per-lane -> ZERO cross-lane reduction, zero DS ops.
// Edge indices: 8/round via broadcast load + readlane -> SGPR addressing;
// round's 16 as/h loads issue back-to-back (indices prefetched a round ahead).
// ---------------------------------------------------------------------------
__global__ __launch_bounds__(256, 8) void aggregate(const int* __restrict__ rowS,
                                                    const int* __restrict__ rowE,
                                                    const int* __restrict__ sortedSrc,
                                                    const short* __restrict__ h,
                                                    const float* __restrict__ as,
                                                    const float* __restrict__ ad,
                                                    const float* __restrict__ bias,
                                                    float* __restrict__ out, int N) {
    const int lane = threadIdx.x & 63;
    const int wv = threadIdx.x >> 6;
    const int node = __builtin_amdgcn_readfirstlane(blockIdx.x * 4 + wv);
    if (node >= N) return;
    const int p = lane >> 3;                 // head of this lane's channels
    const int start = __builtin_amdgcn_readfirstlane(rowS[node]);
    const int end   = __builtin_amdgcn_readfirstlane(rowE[node]);
    const float adv = ad[node * 8 + p];

    float accx = 0.f, accy = 0.f;
    float dsum = 0.f;

    int e = start;
    int iv = node;                            // safe default index
    { int q = e + (lane & 7); if (q < end) iv = sortedSrc[q]; }

    while (e < end) {
        float asv[8]; unsigned hwv[8];
#pragma unroll
        for (int k = 0; k < 8; ++k) {
            int j = __builtin_amdgcn_readlane(iv, k);     // SGPR edge src
            asv[k] = as[j * 8 + p];
            hwv[k] = *(const unsigned*)(h + (size_t)j * 128 + lane * 2);
        }
        int en = e + 8;
        int iv2 = node;
        { int q = en + (lane & 7); if (q < end) iv2 = sortedSrc[q]; }
#pragma unroll
        for (int k = 0; k < 8; ++k) {
            if (e + k < end) {                // scalar branch (e,end uniform)
                float tt = asv[k] + adv;
                tt = tt > 0.f ? tt : NEG_SLOPE * tt;
                float w = __expf(tt);
                unsigned u = hwv[k];
                accx += w * bflo(u);
                accy += w * bfhi(u);
                dsum += w;
            }
        }
        iv = iv2; e = en;
    }

    // self-loop
    {
        float tt = as[node * 8 + p] + adv;
        tt = tt > 0.f ? tt : NEG_SLOPE * tt;
        float w = __expf(tt);
        unsigned u = *(const unsigned*)(h + (size_t)node * 128 + lane * 2);
        accx += w * bflo(u);
        accy += w * bfhi(u);
        dsum += w;
    }

    float inv = 1.0f / (dsum + 1e-16f);
    float2 bv = *(const float2*)(bias + lane * 2);
    float o0 = accx * inv + bv.x;
    float o1 = accy * inv + bv.y;
    o0 = o0 > 0.f ? o0 : 0.f;
    o1 = o1 > 0.f ? o1 : 0.f;
    *(float2*)(out + (size_t)node * 128 + lane * 2) = make_float2(o0, o1);
}

extern "C" void kernel_launch(void* const* d_in, const int* in_sizes, int n_in,
                              void* d_out, int out_size, void* d_ws, size_t ws_size,
                              hipStream_t stream) {
    const float* x     = (const float*)d_in[0];
    const int*   ei    = (const int*)d_in[1];
    const float* W     = (const float*)d_in[2];
    const float* a_src = (const float*)d_in[3];
    const float* a_dst = (const float*)d_in[4];
    const float* bias  = (const float*)d_in[5];
    float* out = (float*)d_out;

    const int N = in_sizes[0] / 128;   // 100000
    const int E = in_sizes[1] / 2;     // 1600000
    const int nEb = (E + 1023) / 1024; // 1563 edge blocks (1024 edges each)
    const int gb  = (N + 63) / 64;     // 1563 gemm blocks
    const int nb1 = (N + 1023) / 1024; // 98 scan blocks (<=128 required)

    char* ws = (char*)d_ws;
    size_t off = 0;
    auto alloc = [&](size_t bytes) { void* p = ws + off; off = (off + bytes + 255) & ~(size_t)255; return p; };
    short* h         = (short*)alloc((size_t)N * 128 * 2);
    float* as        = (float*)alloc((size_t)N * 8 * 4);
    float* ad        = (float*)alloc((size_t)N * 8 * 4);
    int*   deg       = (int*)alloc((size_t)N * 4);
    int*   rowS      = (int*)alloc((size_t)N * 4);
    int*   rowE      = (int*)alloc((size_t)N * 4);
    int*   cur       = (int*)alloc((size_t)N * 4);
    int*   bsum      = (int*)alloc((size_t)128 * 4);
    int*   sortedSrc = (int*)alloc((size_t)E * 4);
    short* WtE       = (short*)alloc((size_t)144 * 128 * 2);

    zero_deg<<<(N + 255) / 256, 256, 0, stream>>>(deg, N);
    prep_count<<<72 + nEb, 256, 0, stream>>>(W, a_src, a_dst, WtE, ei, E, deg);
    scan1<<<nb1, 1024, 0, stream>>>(deg, N, rowS, bsum);
    scan2<<<1, 128, 0, stream>>>(bsum, nb1);
    fixup<<<(N + 255) / 256, 256, 0, stream>>>(deg, bsum, N, rowS, rowE, cur);
    gemm_scatter<<<gb + nEb, 256, 0, stream>>>(x, WtE, h, as, ad, N, gb, ei, E, cur, sortedSrc);
    aggregate<<<(N + 3) / 4, 256, 0, stream>>>(rowS, rowE, sortedSrc, h, as, ad, bias, out, N);
}